// Round 10
// baseline (112.413 us; speedup 1.0000x reference)
//
#include <hip/hip_runtime.h>
#include <math.h>

// SpectralConv2d: out = idht2( mix( dht2(x)[:, :, :32, :32], W ) ) / S^2
// x:  [32][64][128][128] f32   weights1: [64][64][32][32] f32
// out:[32][64][128][128] f32
//
// M is the recursive pseudo-Hartley operator (NOT plain cas(2pi kn/N)):
//   M[k,n] = prod over levels (size Nj = 128,64,...,2):
//     if bit_j(n): (k_j < Nj/2 ? +1 : -1) * cas(2*pi*(k_j mod Nj/2)/Nj), else 1
//     with k_{j+1} = k_j mod (Nj/2).
//
// Pipeline: k_prep (W-transpose + bf16 hi/lo MFMA fragment table) ->
//   k_fwd5 (MFMA; 4 planes per block, grid 512 = exactly 2 blocks/CU,
//   cross-plane register pipeline: plane p+1 loads issued under plane p
//   compute; double-buffered Ybf) -> t_xh -> k_mix4 -> t_blk -> k_inv2.

#define SS   128
#define MD   32
#define NBAT 32
#define CI   64
#define CO   64

#define TWO_PI 6.2831853071795864769

typedef __attribute__((ext_vector_type(8))) short bf16x8;
typedef __attribute__((ext_vector_type(4))) float f32x4;

// ws layout (floats). blk_t aliases Xh; blk aliases Xh_t. ~33.7 MB.
static const size_t OFF_XH   = 32768;                    // 2048*1024
static const size_t OFF_XHT  = 32768 + 2097152;          // 2048*1024
static const size_t OFF_WT   = 32768 + 2 * 2097152;      // 4096*1024
static const size_t OFF_BLKT = OFF_XH;                   // alias
static const size_t OFF_BLK  = OFF_XHT;                  // alias
static const size_t OFF_MFH  = OFF_WT + 4194304;         // 16384 ushort
static const size_t OFF_MFL  = OFF_MFH + 8192;           // 16384 ushort

__device__ inline float m_entry(int k, int n) {
    float prod = 1.f;
    int kk = k, nn = n;
    for (int Nj = SS; Nj > 1; Nj >>= 1) {
        int half = Nj >> 1;
        int k1 = kk & (half - 1);
        if (nn & 1) {
            double ang = (TWO_PI / (double)Nj) * (double)k1;
            float cas = (float)(cos(ang) + sin(ang));
            prod *= (kk < half) ? cas : -cas;
        }
        kk = k1;
        nn >>= 1;
    }
    return prod;
}

__device__ inline unsigned short f2bf(float f) {
    unsigned u = __float_as_uint(f);
    return (unsigned short)((u + 0x7FFF + ((u >> 16) & 1)) >> 16);
}
__device__ inline float bf2f(unsigned short h) {
    return __uint_as_float((unsigned)h << 16);
}
__device__ inline void split2(float a, float b, unsigned& hi, unsigned& lo) {
    unsigned short ah = f2bf(a), bh = f2bf(b);
    hi = (unsigned)ah | ((unsigned)bh << 16);
    lo = (unsigned)f2bf(a - bf2f(ah)) | ((unsigned)f2bf(b - bf2f(bh)) << 16);
}
// fast split: round-half-up hi, truncated lo, packed. ~5 VALU / element.
__device__ inline void fsplit2(float a, float b, unsigned& hi, unsigned& lo) {
    unsigned ua = __float_as_uint(a), ub = __float_as_uint(b);
    unsigned ha = (ua + 0x8000u) & 0xFFFF0000u;
    unsigned hb = (ub + 0x8000u) & 0xFFFF0000u;
    float la = a - __uint_as_float(ha);
    float lb = b - __uint_as_float(hb);
    hi = (ha >> 16) | hb;
    lo = (__float_as_uint(la) >> 16) | (__float_as_uint(lb) & 0xFFFF0000u);
}
__device__ inline bf16x8 pack4(unsigned a, unsigned b, unsigned c, unsigned d) {
    union { unsigned u[4]; bf16x8 v; } w;
    w.u[0] = a; w.u[1] = b; w.u[2] = c; w.u[3] = d;
    return w.v;
}

// blocks 0..4095: transpose wgt -> Wt in 32x32 tiles.
// blocks 4096..4159: MFMA fragment table for M (bf16 hi/lo):
//   entry(tt,s,lane,j) = M[tt*16 + (lane&15)][s*32 + (lane>>4)*8 + j]
__global__ __launch_bounds__(256) void k_prep(const float* __restrict__ wgt,
                                              float* __restrict__ Wt,
                                              unsigned short* __restrict__ MFH,
                                              unsigned short* __restrict__ MFL) {
    const int bid = blockIdx.x;
    const int t   = threadIdx.x;
    if (bid >= 4096) {
        int idx2 = (bid - 4096) * 256 + t;       // 0..16383
        int j    = idx2 & 7;
        int lane = (idx2 >> 3) & 63;
        int s    = (idx2 >> 9) & 3;
        int tt   = idx2 >> 11;                   // 0..7
        int kq   = tt * 16 + (lane & 15);
        int nq   = s * 32 + ((lane >> 4) << 3) + j;
        float f  = m_entry(kq, nq);
        unsigned short hi = f2bf(f);
        MFH[idx2] = hi;
        MFL[idx2] = f2bf(f - bf2f(hi));
        return;
    }
    __shared__ float tile[32][33];
    const int mt  = bid & 31;
    const int iot = bid >> 5;
    const int tx = t & 31;
    const int ty = t >> 5;
#pragma unroll
    for (int j = 0; j < 4; ++j) {
        int r = ty + 8 * j;
        tile[r][tx] = wgt[(iot * 32 + r) * 1024 + mt * 32 + tx];
    }
    __syncthreads();
#pragma unroll
    for (int j = 0; j < 4; ++j) {
        int r = ty + 8 * j;
        Wt[(mt * 32 + r) * 4096 + iot * 32 + tx] = tile[tx][r];
    }
}

// Forward via MFMA; 4 planes per block (grid 512 = 2 resident blocks/CU, no
// tail, no per-plane block ramp). Plane p+1's 16 float4 loads are issued
// while plane p converts/MFMAs/bounces/stores -> HBM latency hidden by ~2000
// cycles of real work for planes 1..3. Ybf double-buffered (1 sync/plane;
// safe: next write to a buffer is separated from its readers by the
// intervening plane's rendezvous barrier).
//   step 1: Y'[h][l] = sum_w X[h][w] * M32[l][w]
//   step 2: Z[k][l]  = sum_h M32[k][h] * Y'[h][l]
__global__ __launch_bounds__(256) void k_fwd5(const float* __restrict__ x,
                                              const unsigned short* __restrict__ MFH,
                                              const unsigned short* __restrict__ MFL,
                                              float* __restrict__ Xh) {
    const int bc0 = blockIdx.x * 4;
    const int t = threadIdx.x;
    const int lane = t & 63, wid = t >> 6;
    const int l15 = lane & 15, g = lane >> 4;

    __shared__ unsigned short Ybf[2][2][32 * 136];  // [buf][hi/lo][l][136 h]

    const int hbase = wid * 32;
    const int ra = (hbase + l15) * 128 + g * 8;       // hh=0 lane base
    const int rb = (hbase + 16 + l15) * 128 + g * 8;  // hh=1 lane base

    float4 xa[2][4][2][2];                       // [parity][s][hh][quad]

    {   // load plane 0
        const float* xp = x + (size_t)bc0 * 16384;
#pragma unroll
        for (int s = 0; s < 4; ++s) {
            xa[0][s][0][0] = *(const float4*)(xp + ra + s * 32);
            xa[0][s][0][1] = *(const float4*)(xp + ra + s * 32 + 4);
            xa[0][s][1][0] = *(const float4*)(xp + rb + s * 32);
            xa[0][s][1][1] = *(const float4*)(xp + rb + s * 32 + 4);
        }
    }

#pragma unroll
    for (int p = 0; p < 4; ++p) {
        const int cur = p & 1;
        if (p < 3) {                              // issue next plane's loads
            const float* xn = x + (size_t)(bc0 + p + 1) * 16384;
#pragma unroll
            for (int s = 0; s < 4; ++s) {
                xa[cur ^ 1][s][0][0] = *(const float4*)(xn + ra + s * 32);
                xa[cur ^ 1][s][0][1] = *(const float4*)(xn + ra + s * 32 + 4);
                xa[cur ^ 1][s][1][0] = *(const float4*)(xn + rb + s * 32);
                xa[cur ^ 1][s][1][1] = *(const float4*)(xn + rb + s * 32 + 4);
            }
        }

        f32x4 acc[2][2] = {};                    // [hh][lt]
#pragma unroll
        for (int s = 0; s < 4; ++s) {
            bf16x8 Bh[2], Bl[2];
#pragma unroll
            for (int lt = 0; lt < 2; ++lt) {
                const int bidx = (lt * 4 + s) * 64 + lane;   // L1-hot table
                Bh[lt] = ((const bf16x8*)MFH)[bidx];
                Bl[lt] = ((const bf16x8*)MFL)[bidx];
            }
#pragma unroll
            for (int hh = 0; hh < 2; ++hh) {
                const float4 v0 = xa[cur][s][hh][0];
                const float4 v1 = xa[cur][s][hh][1];
                unsigned h0, l0, h1, l1, h2, l2, h3, l3;
                fsplit2(v0.x, v0.y, h0, l0);
                fsplit2(v0.z, v0.w, h1, l1);
                fsplit2(v1.x, v1.y, h2, l2);
                fsplit2(v1.z, v1.w, h3, l3);
                const bf16x8 Ah = pack4(h0, h1, h2, h3);
                const bf16x8 Al = pack4(l0, l1, l2, l3);
#pragma unroll
                for (int lt = 0; lt < 2; ++lt) {
                    acc[hh][lt] = __builtin_amdgcn_mfma_f32_16x16x32_bf16(Ah, Bh[lt], acc[hh][lt], 0, 0, 0);
                    acc[hh][lt] = __builtin_amdgcn_mfma_f32_16x16x32_bf16(Ah, Bl[lt], acc[hh][lt], 0, 0, 0);
                    acc[hh][lt] = __builtin_amdgcn_mfma_f32_16x16x32_bf16(Al, Bh[lt], acc[hh][lt], 0, 0, 0);
                }
            }
        }

        // Y' -> bounce LDS buf[cur], bf16 hi/lo, layout [l-mode][h] (136-pad)
#pragma unroll
        for (int hh = 0; hh < 2; ++hh) {
#pragma unroll
            for (int lt = 0; lt < 2; ++lt) {
                int lmode = lt * 16 + l15;            // D col = lane&15
                int h0 = hbase + hh * 16 + g * 4;     // D rows = 4*(lane>>4)+r
                f32x4 v = acc[hh][lt];
                unsigned hi01, lo01, hi23, lo23;
                split2(v[0], v[1], hi01, lo01);
                split2(v[2], v[3], hi23, lo23);
                ((uint2*)&Ybf[cur][0][0])[lmode * 34 + (h0 >> 2)] = make_uint2(hi01, hi23);
                ((uint2*)&Ybf[cur][1][0])[lmode * 34 + (h0 >> 2)] = make_uint2(lo01, lo23);
            }
        }
        __syncthreads();

        // step 2: one 16x16 tile per wave: (kt, lt2)
        const int kt = wid >> 1, lt2 = wid & 1;
        f32x4 z = {};
#pragma unroll
        for (int s2 = 0; s2 < 4; ++s2) {
            int aidx = (kt * 4 + s2) * 64 + lane;
            bf16x8 Ah = ((const bf16x8*)MFH)[aidx];
            bf16x8 Al = ((const bf16x8*)MFL)[aidx];
            int lmode = lt2 * 16 + l15;
            int yidx = lmode * 17 + s2 * 4 + g;       // short8 units
            bf16x8 Yh = ((const bf16x8*)&Ybf[cur][0][0])[yidx];
            bf16x8 Yl = ((const bf16x8*)&Ybf[cur][1][0])[yidx];
            z = __builtin_amdgcn_mfma_f32_16x16x32_bf16(Ah, Yh, z, 0, 0, 0);
            z = __builtin_amdgcn_mfma_f32_16x16x32_bf16(Ah, Yl, z, 0, 0, 0);
            z = __builtin_amdgcn_mfma_f32_16x16x32_bf16(Al, Yh, z, 0, 0, 0);
        }
        float* op = Xh + (size_t)(bc0 + p) * 1024;
#pragma unroll
        for (int r = 0; r < 4; ++r)
            op[(kt * 16 + g * 4 + r) * 32 + lt2 * 16 + l15] = z[r];
    }
}

// Transpose Xh[(b*64+i)][m] -> Xh_t[m][i*32+b].  2048 blocks: (i, m-tile).
__global__ __launch_bounds__(256) void t_xh(const float* __restrict__ Xh,
                                            float* __restrict__ Xh_t) {
    __shared__ float tile[32][33];
    const int i  = blockIdx.x & 63;
    const int mt = blockIdx.x >> 6;
    const int tx = threadIdx.x & 31;
    const int ty = threadIdx.x >> 5;
#pragma unroll
    for (int j = 0; j < 4; ++j) {
        int b = ty + 8 * j;
        tile[b][tx] = Xh[(b * 64 + i) * 1024 + mt * 32 + tx];
    }
    __syncthreads();
#pragma unroll
    for (int j = 0; j < 4; ++j) {
        int row = ty + 8 * j;
        Xh_t[(mt * 32 + row) * 2048 + i * 32 + tx] = tile[tx][row];
    }
}

// Mix, pair-block: block = mode-pair (m, nm). Outputs BOTH modes:
//   out[m]  = x1*We + x1n*Wo,  out[nm] = x1n*We - x1*Wo
__global__ __launch_bounds__(256) void k_mix4(const float* __restrict__ Xh_t,
                                              const float* __restrict__ Wt,
                                              float* __restrict__ blk_t) {
    const int m  = blockIdx.x;
    const int xm = m >> 5, ym = m & 31;
    const int nm = (((32 - xm) & 31) << 5) | ((32 - ym) & 31);
    if (m > nm) return;
    const int t = threadIdx.x;

    __shared__ float Xs[2][64][32];

    {
        const float4* xm4 = (const float4*)(Xh_t + m * 2048);
        const float4* xn4 = (const float4*)(Xh_t + nm * 2048);
        float4* s0 = (float4*)&Xs[0][0][0];
        float4* s1 = (float4*)&Xs[1][0][0];
        s0[t]       = xm4[t];
        s0[t + 256] = xm4[t + 256];
        s1[t]       = xn4[t];
        s1[t + 256] = xn4[t + 256];
    }
    __syncthreads();

    const int o  = t & 63;
    const int bq = t >> 6;
    const float* wpm = Wt + m * 4096 + o;
    const float* wpn = Wt + nm * 4096 + o;

    float am[8], an[8];
#pragma unroll
    for (int j = 0; j < 8; ++j) { am[j] = 0.f; an[j] = 0.f; }

#pragma unroll 4
    for (int i = 0; i < 64; ++i) {
        float wm = wpm[i * 64];
        float wn = wpn[i * 64];
        float we = 0.5f * (wm + wn);
        float wo = 0.5f * (wm - wn);
        const float* xr  = &Xs[0][i][bq * 8];
        const float* xrn = &Xs[1][i][bq * 8];
#pragma unroll
        for (int j = 0; j < 8; ++j) {
            float x1  = xr[j];
            float x1n = xrn[j];
            am[j] = fmaf(x1, we, fmaf(x1n, wo, am[j]));
            an[j] = fmaf(x1n, we, fmaf(x1, -wo, an[j]));
        }
    }

    float* om = blk_t + m * 2048 + o;
    float* on = blk_t + nm * 2048 + o;
#pragma unroll
    for (int j = 0; j < 8; ++j) {
        int b = bq * 8 + j;
        om[b * 64] = am[j];
        on[b * 64] = an[j];
    }
}

// Transpose blk_t[m][bo] -> blk[bo][m].
__global__ __launch_bounds__(256) void t_blk(const float* __restrict__ blk_t,
                                             float* __restrict__ blk) {
    __shared__ float tile[32][33];
    const int mt  = blockIdx.x & 31;
    const int bot = blockIdx.x >> 5;
    const int tx = threadIdx.x & 31;
    const int ty = threadIdx.x >> 5;
#pragma unroll
    for (int j = 0; j < 4; ++j) {
        int r = ty + 8 * j;
        tile[r][tx] = blk_t[(mt * 32 + r) * 2048 + bot * 32 + tx];
    }
    __syncthreads();
#pragma unroll
    for (int j = 0; j < 4; ++j) {
        int r = ty + 8 * j;
        blk[(bot * 32 + r) * 1024 + mt * 32 + tx] = tile[tx][r];
    }
}

// Inverse via MFMA, per (b,o) block (4 waves):
//   step 1: T[r][l] = sum_{h<32} M[r][h] * (blk[h][l]/16384)
//   step 2: out[r][c] = sum_{l<32} T[r][l] * M[c][l]  (out^T tiles, f4 stores)
__global__ __launch_bounds__(256, 2) void k_inv2(const float* __restrict__ blk,
                                                 const unsigned short* __restrict__ MFH,
                                                 const unsigned short* __restrict__ MFL,
                                                 float* __restrict__ out) {
    const int bo = blockIdx.x;
    const int t  = threadIdx.x;
    const int lane = t & 63, wid = t >> 6;
    const int l15 = lane & 15, g = lane >> 4;

    __shared__ __align__(16) unsigned short Bst[2][32 * 40];   // blk^T bf16 [l][h]
    __shared__ __align__(16) unsigned short Tl[2][128 * 40];   // T bf16 [r][l]

    {   // stage blk^T, scaled by 1/16384, split hi/lo
        float4 v = ((const float4*)(blk + (size_t)bo * 1024))[t];
        const int h = t >> 3, l0 = (t & 7) * 4;
        float vv[4] = { v.x * (1.f / 16384.f), v.y * (1.f / 16384.f),
                        v.z * (1.f / 16384.f), v.w * (1.f / 16384.f) };
#pragma unroll
        for (int q = 0; q < 4; ++q) {
            unsigned short hi = f2bf(vv[q]);
            Bst[0][(l0 + q) * 40 + h] = hi;
            Bst[1][(l0 + q) * 40 + h] = f2bf(vv[q] - bf2f(hi));
        }
    }
    __syncthreads();

    // step 1: wave wid owns T rows [wid*32, wid*32+32)
#pragma unroll
    for (int rr = 0; rr < 2; ++rr) {
        const int tt = wid * 2 + rr;
        const int aidx = (tt * 4) * 64 + lane;
        bf16x8 Ah = ((const bf16x8*)MFH)[aidx];
        bf16x8 Al = ((const bf16x8*)MFL)[aidx];
#pragma unroll
        for (int lt = 0; lt < 2; ++lt) {
            bf16x8 Bh = *(const bf16x8*)&Bst[0][(lt * 16 + l15) * 40 + g * 8];
            bf16x8 Bl = *(const bf16x8*)&Bst[1][(lt * 16 + l15) * 40 + g * 8];
            f32x4 acc = {};
            acc = __builtin_amdgcn_mfma_f32_16x16x32_bf16(Ah, Bh, acc, 0, 0, 0);
            acc = __builtin_amdgcn_mfma_f32_16x16x32_bf16(Al, Bh, acc, 0, 0, 0);
            acc = __builtin_amdgcn_mfma_f32_16x16x32_bf16(Ah, Bl, acc, 0, 0, 0);
#pragma unroll
            for (int ri = 0; ri < 4; ++ri) {
                int r = tt * 16 + g * 4 + ri;
                int l = lt * 16 + l15;
                unsigned short hi = f2bf(acc[ri]);
                Tl[0][r * 40 + l] = hi;
                Tl[1][r * 40 + l] = f2bf(acc[ri] - bf2f(hi));
            }
        }
    }
    __syncthreads();

    // step 2: wave wid owns out rows r in [wid*32, wid*32+32); all c.
    float* op = out + (size_t)bo * (SS * SS);
#pragma unroll
    for (int rr = 0; rr < 2; ++rr) {
        const int rt = wid * 2 + rr;
        bf16x8 Bh = *(const bf16x8*)&Tl[0][(rt * 16 + l15) * 40 + g * 8];
        bf16x8 Bl = *(const bf16x8*)&Tl[1][(rt * 16 + l15) * 40 + g * 8];
        const int r = rt * 16 + l15;
#pragma unroll
        for (int ct = 0; ct < 8; ++ct) {
            const int aidx = (ct * 4) * 64 + lane;
            bf16x8 Ah = ((const bf16x8*)MFH)[aidx];
            bf16x8 Al = ((const bf16x8*)MFL)[aidx];
            f32x4 acc = {};
            acc = __builtin_amdgcn_mfma_f32_16x16x32_bf16(Ah, Bh, acc, 0, 0, 0);
            acc = __builtin_amdgcn_mfma_f32_16x16x32_bf16(Al, Bh, acc, 0, 0, 0);
            acc = __builtin_amdgcn_mfma_f32_16x16x32_bf16(Ah, Bl, acc, 0, 0, 0);
            *(float4*)&op[r * SS + ct * 16 + g * 4] =
                make_float4(acc[0], acc[1], acc[2], acc[3]);
        }
    }
}

extern "C" void kernel_launch(void* const* d_in, const int* in_sizes, int n_in,
                              void* d_out, int out_size, void* d_ws, size_t ws_size,
                              hipStream_t stream) {
    const float* x   = (const float*)d_in[0];
    const float* wgt = (const float*)d_in[1];
    float* outp = (float*)d_out;
    float* ws   = (float*)d_ws;

    float* Xh    = ws + OFF_XH;
    float* Xh_t  = ws + OFF_XHT;
    float* Wt    = ws + OFF_WT;
    float* blk_t = ws + OFF_BLKT;
    float* blk   = ws + OFF_BLK;
    unsigned short* MFH = (unsigned short*)(ws + OFF_MFH);
    unsigned short* MFL = (unsigned short*)(ws + OFF_MFL);

    k_prep <<<4160, 256, 0, stream>>>(wgt, Wt, MFH, MFL);
    k_fwd5 <<<512, 256, 0, stream>>>(x, MFH, MFL, Xh);
    t_xh   <<<2048, 256, 0, stream>>>(Xh, Xh_t);
    k_mix4 <<<1024, 256, 0, stream>>>(Xh_t, Wt, blk_t);
    t_blk  <<<2048, 256, 0, stream>>>(blk_t, blk);
    k_inv2 <<<2048, 256, 0, stream>>>(blk, MFH, MFL, outp);
}

// Round 11
// 108.269 us; speedup vs baseline: 1.0383x; 1.0383x over previous
//
#include <hip/hip_runtime.h>
#include <math.h>

// SpectralConv2d: out = idht2( mix( dht2(x)[:, :, :32, :32], W ) ) / S^2
// x:  [32][64][128][128] f32   weights1: [64][64][32][32] f32
// out:[32][64][128][128] f32
//
// M is the recursive pseudo-Hartley operator (NOT plain cas(2pi kn/N)):
//   M[k,n] = prod over levels (size Nj = 128,64,...,2):
//     if bit_j(n): (k_j < Nj/2 ? +1 : -1) * cas(2*pi*(k_j mod Nj/2)/Nj), else 1
//     with k_{j+1} = k_j mod (Nj/2).
//
// Pipeline: k_prep (W-transpose + bf16 hi/lo MFMA fragment table) ->
//   k_fwd6 (MFMA; x staged via global_load_lds width=16 into double-buffered
//   LDS panels, inverse-swizzled source so frag ds_read_b128 is ~4-way;
//   step-1 M-frags preloaded in registers) -> t_xh -> k_mix4 -> t_blk ->
//   k_inv2.

#define SS   128
#define MD   32
#define NBAT 32
#define CI   64
#define CO   64

#define TWO_PI 6.2831853071795864769

typedef __attribute__((ext_vector_type(8))) short bf16x8;
typedef __attribute__((ext_vector_type(4))) float f32x4;

// ws layout (floats). blk_t aliases Xh; blk aliases Xh_t. ~33.7 MB.
static const size_t OFF_XH   = 32768;                    // 2048*1024
static const size_t OFF_XHT  = 32768 + 2097152;          // 2048*1024
static const size_t OFF_WT   = 32768 + 2 * 2097152;      // 4096*1024
static const size_t OFF_BLKT = OFF_XH;                   // alias
static const size_t OFF_BLK  = OFF_XHT;                  // alias
static const size_t OFF_MFH  = OFF_WT + 4194304;         // 16384 ushort
static const size_t OFF_MFL  = OFF_MFH + 8192;           // 16384 ushort

__device__ inline float m_entry(int k, int n) {
    float prod = 1.f;
    int kk = k, nn = n;
    for (int Nj = SS; Nj > 1; Nj >>= 1) {
        int half = Nj >> 1;
        int k1 = kk & (half - 1);
        if (nn & 1) {
            double ang = (TWO_PI / (double)Nj) * (double)k1;
            float cas = (float)(cos(ang) + sin(ang));
            prod *= (kk < half) ? cas : -cas;
        }
        kk = k1;
        nn >>= 1;
    }
    return prod;
}

__device__ inline unsigned short f2bf(float f) {
    unsigned u = __float_as_uint(f);
    return (unsigned short)((u + 0x7FFF + ((u >> 16) & 1)) >> 16);
}
__device__ inline float bf2f(unsigned short h) {
    return __uint_as_float((unsigned)h << 16);
}
__device__ inline void split2(float a, float b, unsigned& hi, unsigned& lo) {
    unsigned short ah = f2bf(a), bh = f2bf(b);
    hi = (unsigned)ah | ((unsigned)bh << 16);
    lo = (unsigned)f2bf(a - bf2f(ah)) | ((unsigned)f2bf(b - bf2f(bh)) << 16);
}
// fast split: round-half-up hi, truncated lo, packed. ~5 VALU / element.
__device__ inline void fsplit2(float a, float b, unsigned& hi, unsigned& lo) {
    unsigned ua = __float_as_uint(a), ub = __float_as_uint(b);
    unsigned ha = (ua + 0x8000u) & 0xFFFF0000u;
    unsigned hb = (ub + 0x8000u) & 0xFFFF0000u;
    float la = a - __uint_as_float(ha);
    float lb = b - __uint_as_float(hb);
    hi = (ha >> 16) | hb;
    lo = (__float_as_uint(la) >> 16) | (__float_as_uint(lb) & 0xFFFF0000u);
}
__device__ inline bf16x8 pack4(unsigned a, unsigned b, unsigned c, unsigned d) {
    union { unsigned u[4]; bf16x8 v; } w;
    w.u[0] = a; w.u[1] = b; w.u[2] = c; w.u[3] = d;
    return w.v;
}

// blocks 0..4095: transpose wgt -> Wt in 32x32 tiles.
// blocks 4096..4159: MFMA fragment table for M (bf16 hi/lo):
//   entry(tt,s,lane,j) = M[tt*16 + (lane&15)][s*32 + (lane>>4)*8 + j]
__global__ __launch_bounds__(256) void k_prep(const float* __restrict__ wgt,
                                              float* __restrict__ Wt,
                                              unsigned short* __restrict__ MFH,
                                              unsigned short* __restrict__ MFL) {
    const int bid = blockIdx.x;
    const int t   = threadIdx.x;
    if (bid >= 4096) {
        int idx2 = (bid - 4096) * 256 + t;       // 0..16383
        int j    = idx2 & 7;
        int lane = (idx2 >> 3) & 63;
        int s    = (idx2 >> 9) & 3;
        int tt   = idx2 >> 11;                   // 0..7
        int kq   = tt * 16 + (lane & 15);
        int nq   = s * 32 + ((lane >> 4) << 3) + j;
        float f  = m_entry(kq, nq);
        unsigned short hi = f2bf(f);
        MFH[idx2] = hi;
        MFL[idx2] = f2bf(f - bf2f(hi));
        return;
    }
    __shared__ float tile[32][33];
    const int mt  = bid & 31;
    const int iot = bid >> 5;
    const int tx = t & 31;
    const int ty = t >> 5;
#pragma unroll
    for (int j = 0; j < 4; ++j) {
        int r = ty + 8 * j;
        tile[r][tx] = wgt[(iot * 32 + r) * 1024 + mt * 32 + tx];
    }
    __syncthreads();
#pragma unroll
    for (int j = 0; j < 4; ++j) {
        int r = ty + 8 * j;
        Wt[(mt * 32 + r) * 4096 + iot * 32 + tx] = tile[tx][r];
    }
}

// Forward via MFMA; x staged with global_load_lds width=16 (async DMA, no
// VGPR round-trip), double-buffered 16KB column-panels, 1 barrier per panel.
// LDS dest is linear (HW: wave-uniform base + lane*16); the 32B chunks are
// inverse-swizzled on the GLOBAL source (chunk ^= row&3) so the frag read
// (ds_read_b128 at row*128B + chunk*32B) is ~4-way instead of 16-way banked.
// Step-1 M-fragment table preloaded into 64 VGPRs (zero inner-loop global).
//   step 1: Y'[h][l] = sum_w X[h][w] * M32[l][w]
//   step 2: Z[k][l]  = sum_h M32[k][h] * Y'[h][l]
__global__ __launch_bounds__(256, 2) void k_fwd6(const float* __restrict__ x,
                                                 const unsigned short* __restrict__ MFH,
                                                 const unsigned short* __restrict__ MFL,
                                                 float* __restrict__ Xh) {
    const int bc = blockIdx.x;
    const float* xp = x + (size_t)bc * 16384;
    const int t = threadIdx.x;
    const int lane = t & 63, wid = t >> 6;
    const int l15 = lane & 15, g = lane >> 4;

    __shared__ __align__(16) float Pan[2][4096];        // 2 x 16KB panels
    __shared__ __align__(16) unsigned short Ybf[2][32 * 136];

    // preload step-1 B-frag table (loop-invariant, 64 VGPR)
    bf16x8 TBh[2][4], TBl[2][4];
#pragma unroll
    for (int lt = 0; lt < 2; ++lt)
#pragma unroll
        for (int s = 0; s < 4; ++s) {
            const int bidx = (lt * 4 + s) * 64 + lane;
            TBh[lt][s] = ((const bf16x8*)MFH)[bidx];
            TBl[lt][s] = ((const bf16x8*)MFL)[bidx];
        }

    // staging: slot16 = j*256 + wid*64 + lane; row = slot16>>3; s16 = slot16&7
    // gchunk = (s16>>1) ^ (row&3); 16B from xp + row*512 + s*128 + gchunk*32
    // + (s16&1)*16 -> LDS linear at Pan[buf] + j*4096 + wid*1024 + lane*16.
    const int slot  = wid * 64 + lane;
    const int srow  = slot >> 3, s16 = slot & 7;
    const int sbyte0 = srow * 512 + (((s16 >> 1) ^ (srow & 3)) * 32) + (s16 & 1) * 16;

#define STAGE(buf, sp)                                                         \
    {                                                                          \
        _Pragma("unroll")                                                      \
        for (int j = 0; j < 4; ++j) {                                          \
            int slot2 = j * 256 + slot;                                        \
            int row2 = slot2 >> 3, t16 = slot2 & 7;                            \
            const char* gp = (const char*)xp + row2 * 512 + (sp) * 128 +       \
                             (((t16 >> 1) ^ (row2 & 3)) * 32) + (t16 & 1) * 16;\
            char* lp = (char*)&Pan[buf][0] + j * 4096 + wid * 1024;            \
            __builtin_amdgcn_global_load_lds(                                  \
                (const __attribute__((address_space(1))) void*)gp,             \
                (__attribute__((address_space(3))) void*)lp, 16, 0, 0);        \
        }                                                                      \
    }
    (void)sbyte0;

    f32x4 acc[2][2] = {};                        // [hh][lt]
    const int hbase = wid * 32;

    STAGE(0, 0);
#pragma unroll
    for (int s = 0; s < 4; ++s) {
        const int cur = s & 1;
        __syncthreads();                          // panel[cur] ready
        if (s < 3) STAGE(cur ^ 1, s + 1);         // overlap with compute
#pragma unroll
        for (int hh = 0; hh < 2; ++hh) {
            const int row = hbase + hh * 16 + l15;
            const float* pr = &Pan[cur][row * 32 + ((g ^ (row & 3)) * 8)];
            const float4 v0 = *(const float4*)pr;
            const float4 v1 = *(const float4*)(pr + 4);
            unsigned h0, l0, h1, l1, h2, l2, h3, l3;
            fsplit2(v0.x, v0.y, h0, l0);
            fsplit2(v0.z, v0.w, h1, l1);
            fsplit2(v1.x, v1.y, h2, l2);
            fsplit2(v1.z, v1.w, h3, l3);
            const bf16x8 Ah = pack4(h0, h1, h2, h3);
            const bf16x8 Al = pack4(l0, l1, l2, l3);
#pragma unroll
            for (int lt = 0; lt < 2; ++lt) {
                acc[hh][lt] = __builtin_amdgcn_mfma_f32_16x16x32_bf16(Ah, TBh[lt][s], acc[hh][lt], 0, 0, 0);
                acc[hh][lt] = __builtin_amdgcn_mfma_f32_16x16x32_bf16(Ah, TBl[lt][s], acc[hh][lt], 0, 0, 0);
                acc[hh][lt] = __builtin_amdgcn_mfma_f32_16x16x32_bf16(Al, TBh[lt][s], acc[hh][lt], 0, 0, 0);
            }
        }
    }

    // Y' -> bounce LDS, split to bf16 hi/lo, layout [l-mode][h] (136-padded)
#pragma unroll
    for (int hh = 0; hh < 2; ++hh) {
#pragma unroll
        for (int lt = 0; lt < 2; ++lt) {
            int lmode = lt * 16 + l15;            // D col = lane&15
            int h0 = hbase + hh * 16 + g * 4;     // D rows = 4*(lane>>4)+r
            f32x4 v = acc[hh][lt];
            unsigned hi01, lo01, hi23, lo23;
            split2(v[0], v[1], hi01, lo01);
            split2(v[2], v[3], hi23, lo23);
            ((uint2*)&Ybf[0][0])[lmode * 34 + (h0 >> 2)] = make_uint2(hi01, hi23);
            ((uint2*)&Ybf[1][0])[lmode * 34 + (h0 >> 2)] = make_uint2(lo01, lo23);
        }
    }
    __syncthreads();

    // step 2: one 16x16 tile per wave: (kt, lt2)
    const int kt = wid >> 1, lt2 = wid & 1;
    f32x4 z = {};
#pragma unroll
    for (int s2 = 0; s2 < 4; ++s2) {
        int aidx = (kt * 4 + s2) * 64 + lane;
        bf16x8 Ah = ((const bf16x8*)MFH)[aidx];
        bf16x8 Al = ((const bf16x8*)MFL)[aidx];
        int lmode = lt2 * 16 + l15;
        int yidx = lmode * 17 + s2 * 4 + g;       // short8 units, 16B aligned
        bf16x8 Yh = ((const bf16x8*)&Ybf[0][0])[yidx];
        bf16x8 Yl = ((const bf16x8*)&Ybf[1][0])[yidx];
        z = __builtin_amdgcn_mfma_f32_16x16x32_bf16(Ah, Yh, z, 0, 0, 0);
        z = __builtin_amdgcn_mfma_f32_16x16x32_bf16(Ah, Yl, z, 0, 0, 0);
        z = __builtin_amdgcn_mfma_f32_16x16x32_bf16(Al, Yh, z, 0, 0, 0);
    }
    float* op = Xh + (size_t)bc * 1024;
#pragma unroll
    for (int r = 0; r < 4; ++r)
        op[(kt * 16 + g * 4 + r) * 32 + lt2 * 16 + l15] = z[r];
#undef STAGE
}

// Transpose Xh[(b*64+i)][m] -> Xh_t[m][i*32+b].  2048 blocks: (i, m-tile).
__global__ __launch_bounds__(256) void t_xh(const float* __restrict__ Xh,
                                            float* __restrict__ Xh_t) {
    __shared__ float tile[32][33];
    const int i  = blockIdx.x & 63;
    const int mt = blockIdx.x >> 6;
    const int tx = threadIdx.x & 31;
    const int ty = threadIdx.x >> 5;
#pragma unroll
    for (int j = 0; j < 4; ++j) {
        int b = ty + 8 * j;
        tile[b][tx] = Xh[(b * 64 + i) * 1024 + mt * 32 + tx];
    }
    __syncthreads();
#pragma unroll
    for (int j = 0; j < 4; ++j) {
        int row = ty + 8 * j;
        Xh_t[(mt * 32 + row) * 2048 + i * 32 + tx] = tile[tx][row];
    }
}

// Mix, pair-block: block = mode-pair (m, nm). Outputs BOTH modes:
//   out[m]  = x1*We + x1n*Wo,  out[nm] = x1n*We - x1*Wo
__global__ __launch_bounds__(256) void k_mix4(const float* __restrict__ Xh_t,
                                              const float* __restrict__ Wt,
                                              float* __restrict__ blk_t) {
    const int m  = blockIdx.x;
    const int xm = m >> 5, ym = m & 31;
    const int nm = (((32 - xm) & 31) << 5) | ((32 - ym) & 31);
    if (m > nm) return;
    const int t = threadIdx.x;

    __shared__ float Xs[2][64][32];

    {
        const float4* xm4 = (const float4*)(Xh_t + m * 2048);
        const float4* xn4 = (const float4*)(Xh_t + nm * 2048);
        float4* s0 = (float4*)&Xs[0][0][0];
        float4* s1 = (float4*)&Xs[1][0][0];
        s0[t]       = xm4[t];
        s0[t + 256] = xm4[t + 256];
        s1[t]       = xn4[t];
        s1[t + 256] = xn4[t + 256];
    }
    __syncthreads();

    const int o  = t & 63;
    const int bq = t >> 6;
    const float* wpm = Wt + m * 4096 + o;
    const float* wpn = Wt + nm * 4096 + o;

    float am[8], an[8];
#pragma unroll
    for (int j = 0; j < 8; ++j) { am[j] = 0.f; an[j] = 0.f; }

#pragma unroll 4
    for (int i = 0; i < 64; ++i) {
        float wm = wpm[i * 64];
        float wn = wpn[i * 64];
        float we = 0.5f * (wm + wn);
        float wo = 0.5f * (wm - wn);
        const float* xr  = &Xs[0][i][bq * 8];
        const float* xrn = &Xs[1][i][bq * 8];
#pragma unroll
        for (int j = 0; j < 8; ++j) {
            float x1  = xr[j];
            float x1n = xrn[j];
            am[j] = fmaf(x1, we, fmaf(x1n, wo, am[j]));
            an[j] = fmaf(x1n, we, fmaf(x1, -wo, an[j]));
        }
    }

    float* om = blk_t + m * 2048 + o;
    float* on = blk_t + nm * 2048 + o;
#pragma unroll
    for (int j = 0; j < 8; ++j) {
        int b = bq * 8 + j;
        om[b * 64] = am[j];
        on[b * 64] = an[j];
    }
}

// Transpose blk_t[m][bo] -> blk[bo][m].
__global__ __launch_bounds__(256) void t_blk(const float* __restrict__ blk_t,
                                             float* __restrict__ blk) {
    __shared__ float tile[32][33];
    const int mt  = blockIdx.x & 31;
    const int bot = blockIdx.x >> 5;
    const int tx = threadIdx.x & 31;
    const int ty = threadIdx.x >> 5;
#pragma unroll
    for (int j = 0; j < 4; ++j) {
        int r = ty + 8 * j;
        tile[r][tx] = blk_t[(mt * 32 + r) * 2048 + bot * 32 + tx];
    }
    __syncthreads();
#pragma unroll
    for (int j = 0; j < 4; ++j) {
        int r = ty + 8 * j;
        blk[(bot * 32 + r) * 1024 + mt * 32 + tx] = tile[tx][r];
    }
}

// Inverse via MFMA, per (b,o) block (4 waves):
//   step 1: T[r][l] = sum_{h<32} M[r][h] * (blk[h][l]/16384)
//   step 2: out[r][c] = sum_{l<32} T[r][l] * M[c][l]  (out^T tiles, f4 stores)
__global__ __launch_bounds__(256, 2) void k_inv2(const float* __restrict__ blk,
                                                 const unsigned short* __restrict__ MFH,
                                                 const unsigned short* __restrict__ MFL,
                                                 float* __restrict__ out) {
    const int bo = blockIdx.x;
    const int t  = threadIdx.x;
    const int lane = t & 63, wid = t >> 6;
    const int l15 = lane & 15, g = lane >> 4;

    __shared__ __align__(16) unsigned short Bst[2][32 * 40];   // blk^T bf16 [l][h]
    __shared__ __align__(16) unsigned short Tl[2][128 * 40];   // T bf16 [r][l]

    {   // stage blk^T, scaled by 1/16384, split hi/lo
        float4 v = ((const float4*)(blk + (size_t)bo * 1024))[t];
        const int h = t >> 3, l0 = (t & 7) * 4;
        float vv[4] = { v.x * (1.f / 16384.f), v.y * (1.f / 16384.f),
                        v.z * (1.f / 16384.f), v.w * (1.f / 16384.f) };
#pragma unroll
        for (int q = 0; q < 4; ++q) {
            unsigned short hi = f2bf(vv[q]);
            Bst[0][(l0 + q) * 40 + h] = hi;
            Bst[1][(l0 + q) * 40 + h] = f2bf(vv[q] - bf2f(hi));
        }
    }
    __syncthreads();

    // step 1: wave wid owns T rows [wid*32, wid*32+32)
#pragma unroll
    for (int rr = 0; rr < 2; ++rr) {
        const int tt = wid * 2 + rr;
        const int aidx = (tt * 4) * 64 + lane;
        bf16x8 Ah = ((const bf16x8*)MFH)[aidx];
        bf16x8 Al = ((const bf16x8*)MFL)[aidx];
#pragma unroll
        for (int lt = 0; lt < 2; ++lt) {
            bf16x8 Bh = *(const bf16x8*)&Bst[0][(lt * 16 + l15) * 40 + g * 8];
            bf16x8 Bl = *(const bf16x8*)&Bst[1][(lt * 16 + l15) * 40 + g * 8];
            f32x4 acc = {};
            acc = __builtin_amdgcn_mfma_f32_16x16x32_bf16(Ah, Bh, acc, 0, 0, 0);
            acc = __builtin_amdgcn_mfma_f32_16x16x32_bf16(Al, Bh, acc, 0, 0, 0);
            acc = __builtin_amdgcn_mfma_f32_16x16x32_bf16(Ah, Bl, acc, 0, 0, 0);
#pragma unroll
            for (int ri = 0; ri < 4; ++ri) {
                int r = tt * 16 + g * 4 + ri;
                int l = lt * 16 + l15;
                unsigned short hi = f2bf(acc[ri]);
                Tl[0][r * 40 + l] = hi;
                Tl[1][r * 40 + l] = f2bf(acc[ri] - bf2f(hi));
            }
        }
    }
    __syncthreads();

    // step 2: wave wid owns out rows r in [wid*32, wid*32+32); all c.
    float* op = out + (size_t)bo * (SS * SS);
#pragma unroll
    for (int rr = 0; rr < 2; ++rr) {
        const int rt = wid * 2 + rr;
        bf16x8 Bh = *(const bf16x8*)&Tl[0][(rt * 16 + l15) * 40 + g * 8];
        bf16x8 Bl = *(const bf16x8*)&Tl[1][(rt * 16 + l15) * 40 + g * 8];
        const int r = rt * 16 + l15;
#pragma unroll
        for (int ct = 0; ct < 8; ++ct) {
            const int aidx = (ct * 4) * 64 + lane;
            bf16x8 Ah = ((const bf16x8*)MFH)[aidx];
            bf16x8 Al = ((const bf16x8*)MFL)[aidx];
            f32x4 acc = {};
            acc = __builtin_amdgcn_mfma_f32_16x16x32_bf16(Ah, Bh, acc, 0, 0, 0);
            acc = __builtin_amdgcn_mfma_f32_16x16x32_bf16(Al, Bh, acc, 0, 0, 0);
            acc = __builtin_amdgcn_mfma_f32_16x16x32_bf16(Ah, Bl, acc, 0, 0, 0);
            *(float4*)&op[r * SS + ct * 16 + g * 4] =
                make_float4(acc[0], acc[1], acc[2], acc[3]);
        }
    }
}

extern "C" void kernel_launch(void* const* d_in, const int* in_sizes, int n_in,
                              void* d_out, int out_size, void* d_ws, size_t ws_size,
                              hipStream_t stream) {
    const float* x   = (const float*)d_in[0];
    const float* wgt = (const float*)d_in[1];
    float* outp = (float*)d_out;
    float* ws   = (float*)d_ws;

    float* Xh    = ws + OFF_XH;
    float* Xh_t  = ws + OFF_XHT;
    float* Wt    = ws + OFF_WT;
    float* blk_t = ws + OFF_BLKT;
    float* blk   = ws + OFF_BLK;
    unsigned short* MFH = (unsigned short*)(ws + OFF_MFH);
    unsigned short* MFL = (unsigned short*)(ws + OFF_MFL);

    k_prep <<<4160, 256, 0, stream>>>(wgt, Wt, MFH, MFL);
    k_fwd6 <<<2048, 256, 0, stream>>>(x, MFH, MFL, Xh);
    t_xh   <<<2048, 256, 0, stream>>>(Xh, Xh_t);
    k_mix4 <<<1024, 256, 0, stream>>>(Xh_t, Wt, blk_t);
    t_blk  <<<2048, 256, 0, stream>>>(blk_t, blk);
    k_inv2 <<<2048, 256, 0, stream>>>(blk, MFH, MFL, outp);
}